// Round 1
// baseline (671.835 us; speedup 1.0000x reference)
//
#include <hip/hip_runtime.h>
#include <hip/hip_bf16.h>

typedef __attribute__((ext_vector_type(8))) short short8;
typedef __attribute__((ext_vector_type(4))) ushort ushort4v;
typedef __attribute__((ext_vector_type(4))) float f32x4;

#define MFMA16(A, B, C) __builtin_amdgcn_mfma_f32_16x16x32_bf16(A, B, C, 0, 0, 0)

static constexpr int Lx = 2048, Dx = 2048, Hx = 16, HDx = 128, NBx = 2;

__device__ __forceinline__ ushort f2bu(float f) {
  __hip_bfloat16 h = __float2bfloat16(f);
  union { __hip_bfloat16 h; ushort u; } v;
  v.h = h;
  return v.u;
}

__device__ __forceinline__ short8 pack8(const float4& a, const float4& b) {
  short8 r;
  r[0] = (short)f2bu(a.x); r[1] = (short)f2bu(a.y);
  r[2] = (short)f2bu(a.z); r[3] = (short)f2bu(a.w);
  r[4] = (short)f2bu(b.x); r[5] = (short)f2bu(b.y);
  r[6] = (short)f2bu(b.z); r[7] = (short)f2bu(b.w);
  return r;
}

// ---------------------------------------------------------------------------
// QKV projection: q/k/v = x @ W.T + b, fused bias + partial rotary + q-scale.
// 128x128 tile, BK=32, 4 waves (2x2), bf16 MFMA, reg-staged f32->bf16.
// ---------------------------------------------------------------------------
__global__ __launch_bounds__(256, 2) void qkv_kernel(
    const float* __restrict__ x,
    const float* __restrict__ Wq, const float* __restrict__ bq,
    const float* __restrict__ Wk, const float* __restrict__ bk,
    const float* __restrict__ Wv, const float* __restrict__ bv,
    const float* __restrict__ sinT, const float* __restrict__ cosT,
    ushort* __restrict__ qw, ushort* __restrict__ kw, ushort* __restrict__ vw) {
  const int z = blockIdx.z;
  const float* W    = (z == 0) ? Wq : (z == 1) ? Wk : Wv;
  const float* bias = (z == 0) ? bq : (z == 1) ? bk : bv;
  ushort* outp      = (z == 0) ? qw : (z == 1) ? kw : vw;

  const int bm = blockIdx.x, bn = blockIdx.y;
  const int tid = threadIdx.x;

  __shared__ ushort As[2][128][40];  // stride 40 elems (80B): conflict-free b128 reads
  __shared__ ushort Bs[2][128][40];

  const int srow = tid >> 1;
  const int skh = (tid & 1) * 16;
  const float* ag = x + (size_t)(bm * 128 + srow) * Dx + skh;
  const float* bg = W + (size_t)(bn * 128 + srow) * Dx + skh;

  const int l15 = tid & 15, hi = (tid >> 4) & 3;
  const int w = tid >> 6;
  const int wm = (w >> 1) * 64, wn = (w & 1) * 64;

  f32x4 acc[4][4];
#pragma unroll
  for (int i = 0; i < 4; ++i)
#pragma unroll
    for (int j = 0; j < 4; ++j) acc[i][j] = {0.f, 0.f, 0.f, 0.f};

  // prologue: stage tile 0 into buffer 0
  {
    float4 a0 = *(const float4*)(ag + 0), a1 = *(const float4*)(ag + 4);
    float4 a2 = *(const float4*)(ag + 8), a3 = *(const float4*)(ag + 12);
    float4 b0 = *(const float4*)(bg + 0), b1 = *(const float4*)(bg + 4);
    float4 b2 = *(const float4*)(bg + 8), b3 = *(const float4*)(bg + 12);
    *(short8*)&As[0][srow][skh] = pack8(a0, a1);
    *(short8*)&As[0][srow][skh + 8] = pack8(a2, a3);
    *(short8*)&Bs[0][srow][skh] = pack8(b0, b1);
    *(short8*)&Bs[0][srow][skh + 8] = pack8(b2, b3);
  }
  __syncthreads();

  int cur = 0;
  for (int kt = 0; kt < 64; ++kt) {
    float4 a0, a1, a2, a3, b0, b1, b2, b3;
    if (kt < 63) {  // issue next tile's global loads early (latency under MFMA)
      const float* ap = ag + (kt + 1) * 32;
      const float* bp = bg + (kt + 1) * 32;
      a0 = *(const float4*)(ap + 0); a1 = *(const float4*)(ap + 4);
      a2 = *(const float4*)(ap + 8); a3 = *(const float4*)(ap + 12);
      b0 = *(const float4*)(bp + 0); b1 = *(const float4*)(bp + 4);
      b2 = *(const float4*)(bp + 8); b3 = *(const float4*)(bp + 12);
    }
    short8 af[4], bf[4];
#pragma unroll
    for (int i = 0; i < 4; ++i)
      af[i] = *(const short8*)&As[cur][wm + i * 16 + l15][hi * 8];
#pragma unroll
    for (int j = 0; j < 4; ++j)
      bf[j] = *(const short8*)&Bs[cur][wn + j * 16 + l15][hi * 8];
#pragma unroll
    for (int i = 0; i < 4; ++i)
#pragma unroll
      for (int j = 0; j < 4; ++j) acc[i][j] = MFMA16(af[i], bf[j], acc[i][j]);
    if (kt < 63) {
      *(short8*)&As[cur ^ 1][srow][skh] = pack8(a0, a1);
      *(short8*)&As[cur ^ 1][srow][skh + 8] = pack8(a2, a3);
      *(short8*)&Bs[cur ^ 1][srow][skh] = pack8(b0, b1);
      *(short8*)&Bs[cur ^ 1][srow][skh + 8] = pack8(b2, b3);
    }
    __syncthreads();
    cur ^= 1;
  }

  // epilogue: bias + rotary(first half of each head, q&k) + q scale; bf16 [B,H,L,HD]
  const float rsHD = 0.08838834764831845f;  // 1/sqrt(128)
#pragma unroll
  for (int j = 0; j < 4; ++j) {
    const int n = bn * 128 + wn + j * 16 + l15;
    const int h = n >> 7, d = n & 127;
    const float bb = bias[n];
#pragma unroll
    for (int i = 0; i < 4; ++i) {
#pragma unroll
      for (int r = 0; r < 4; ++r) {
        const int m = bm * 128 + wm + i * 16 + hi * 4 + r;
        const int b = m >> 11, l = m & (Lx - 1);
        float v = acc[i][j][r] + bb;
        if (z < 2 && d < 64) v *= (cosT[l * 64 + d] - sinT[l * 64 + d]);
        if (z == 0) v *= rsHD;
        outp[(size_t)((b * Hx + h) * Lx + l) * HDx + d] = f2bu(v);
      }
    }
  }
}

// ---------------------------------------------------------------------------
// Causal flash attention. 4 waves x 16 q-rows (QBLK=64), KVBLK=64, bf16 MFMA.
// Q in registers; K staged padded; V transposed in LDS; wave-parallel softmax.
// ---------------------------------------------------------------------------
__global__ __launch_bounds__(256, 2) void attn_kernel(
    const ushort* __restrict__ qw, const ushort* __restrict__ kw,
    const ushort* __restrict__ vw, ushort* __restrict__ ctx) {
  const int qt = (int)(gridDim.x - 1) - (int)blockIdx.x;  // heavy tiles first
  const int bh = blockIdx.y;
  const int b = bh >> 4, h = bh & 15;
  const int tid = threadIdx.x;
  const int w = tid >> 6, l15 = tid & 15, hi = (tid >> 4) & 3;

  const ushort* Q = qw + (size_t)bh * Lx * HDx;
  const ushort* K = kw + (size_t)bh * Lx * HDx;
  const ushort* V = vw + (size_t)bh * Lx * HDx;

  __shared__ ushort Ks[64][136];   // pad: stride 272B, conflict-free frag reads
  __shared__ ushort Vt[128][72];   // transposed V, stride 144B
  __shared__ ushort Ps[4][16][72]; // per-wave P buffer

  short8 qf[4];
  {
    const ushort* qr = Q + (size_t)(qt * 64 + w * 16 + l15) * HDx + hi * 8;
#pragma unroll
    for (int ds = 0; ds < 4; ++ds) qf[ds] = *(const short8*)(qr + ds * 32);
  }

  f32x4 o[8];
#pragma unroll
  for (int df = 0; df < 8; ++df) o[df] = {0.f, 0.f, 0.f, 0.f};
  float mr[4], lr[4];
#pragma unroll
  for (int r = 0; r < 4; ++r) { mr[r] = -1e30f; lr[r] = 0.f; }

  const int skrow = tid >> 2, skd = (tid & 3) * 32;     // K staging
  const int svk = (tid & 15) * 4, svd = (tid >> 4) * 8; // V staging

  for (int kv = 0; kv <= qt; ++kv) {
    __syncthreads();  // previous tile's LDS reads complete
    {   // stage K tile [64][128] (coalesced rows)
      const ushort* kp = K + (size_t)(kv * 64 + skrow) * HDx + skd;
      short8 k0 = *(const short8*)(kp + 0), k1 = *(const short8*)(kp + 8);
      short8 k2 = *(const short8*)(kp + 16), k3 = *(const short8*)(kp + 24);
      *(short8*)&Ks[skrow][skd + 0] = k0;
      *(short8*)&Ks[skrow][skd + 8] = k1;
      *(short8*)&Ks[skrow][skd + 16] = k2;
      *(short8*)&Ks[skrow][skd + 24] = k3;
    }
    {   // stage V transposed: Vt[d][k]
      const ushort* vp = V + (size_t)(kv * 64 + svk) * HDx + svd;
      short8 r0 = *(const short8*)(vp);
      short8 r1 = *(const short8*)(vp + HDx);
      short8 r2 = *(const short8*)(vp + 2 * HDx);
      short8 r3 = *(const short8*)(vp + 3 * HDx);
#pragma unroll
      for (int j = 0; j < 8; ++j) {
        ushort4v pk;
        pk[0] = (ushort)r0[j]; pk[1] = (ushort)r1[j];
        pk[2] = (ushort)r2[j]; pk[3] = (ushort)r3[j];
        *(ushort4v*)&Vt[svd + j][svk] = pk;
      }
    }
    __syncthreads();

    // S = Q K^T  (16 q-rows x 64 k-cols per wave)
    f32x4 s[4];
#pragma unroll
    for (int kf = 0; kf < 4; ++kf) s[kf] = {0.f, 0.f, 0.f, 0.f};
#pragma unroll
    for (int kf = 0; kf < 4; ++kf)
#pragma unroll
      for (int ds = 0; ds < 4; ++ds) {
        short8 kb = *(const short8*)&Ks[kf * 16 + l15][ds * 32 + hi * 8];
        s[kf] = MFMA16(qf[ds], kb, s[kf]);
      }

    if (kv == qt) {  // diagonal tile: causal mask
#pragma unroll
      for (int kf = 0; kf < 4; ++kf)
#pragma unroll
        for (int r = 0; r < 4; ++r)
          if (kf * 16 + l15 > w * 16 + hi * 4 + r) s[kf][r] = -1e30f;
    }

    // online softmax (row = q). Row spread over 16 lanes (l15) x 4 kf frags.
    float ml[4];
#pragma unroll
    for (int r = 0; r < 4; ++r)
      ml[r] = fmaxf(fmaxf(s[0][r], s[1][r]), fmaxf(s[2][r], s[3][r]));
#pragma unroll
    for (int off = 1; off <= 8; off <<= 1)
#pragma unroll
      for (int r = 0; r < 4; ++r) ml[r] = fmaxf(ml[r], __shfl_xor(ml[r], off));
    float scl[4];
#pragma unroll
    for (int r = 0; r < 4; ++r) {
      float mn = fmaxf(mr[r], ml[r]);
      scl[r] = __expf(mr[r] - mn);
      mr[r] = mn;
    }
    float ll[4] = {0.f, 0.f, 0.f, 0.f};
#pragma unroll
    for (int kf = 0; kf < 4; ++kf)
#pragma unroll
      for (int r = 0; r < 4; ++r) {
        float p = __expf(s[kf][r] - mr[r]);
        s[kf][r] = p;
        ll[r] += p;
      }
#pragma unroll
    for (int off = 1; off <= 8; off <<= 1)
#pragma unroll
      for (int r = 0; r < 4; ++r) ll[r] += __shfl_xor(ll[r], off);
#pragma unroll
    for (int r = 0; r < 4; ++r) lr[r] = lr[r] * scl[r] + ll[r];
#pragma unroll
    for (int df = 0; df < 8; ++df)
#pragma unroll
      for (int r = 0; r < 4; ++r) o[df][r] *= scl[r];

    // P -> per-wave LDS (C-layout -> A-layout fix)
#pragma unroll
    for (int kf = 0; kf < 4; ++kf)
#pragma unroll
      for (int r = 0; r < 4; ++r)
        Ps[w][hi * 4 + r][kf * 16 + l15] = f2bu(s[kf][r]);

    short8 pa0 = *(const short8*)&Ps[w][l15][hi * 8];
    short8 pa1 = *(const short8*)&Ps[w][l15][32 + hi * 8];
#pragma unroll
    for (int df = 0; df < 8; ++df) {
      short8 v0 = *(const short8*)&Vt[df * 16 + l15][hi * 8];
      short8 v1 = *(const short8*)&Vt[df * 16 + l15][32 + hi * 8];
      o[df] = MFMA16(pa0, v0, o[df]);
      o[df] = MFMA16(pa1, v1, o[df]);
    }
  }

  // epilogue: ctx[b][l][h*128+d] bf16
  float inv[4];
#pragma unroll
  for (int r = 0; r < 4; ++r) inv[r] = 1.0f / lr[r];
  ushort* cp = ctx + (size_t)(b * Lx + qt * 64 + w * 16) * Dx + h * HDx;
#pragma unroll
  for (int df = 0; df < 8; ++df)
#pragma unroll
    for (int r = 0; r < 4; ++r)
      cp[(size_t)(hi * 4 + r) * Dx + df * 16 + l15] = f2bu(o[df][r] * inv[r]);
}

// ---------------------------------------------------------------------------
// Output projection: out = ctx @ Wo.T + bo (A bf16, B f32->bf16, out f32)
// ---------------------------------------------------------------------------
__global__ __launch_bounds__(256, 2) void oproj_kernel(
    const ushort* __restrict__ ctx, const float* __restrict__ Wo,
    const float* __restrict__ bo, float* __restrict__ out) {
  const int bm = blockIdx.x, bn = blockIdx.y;
  const int tid = threadIdx.x;

  __shared__ ushort As[2][128][40];
  __shared__ ushort Bs[2][128][40];

  const int srow = tid >> 1;
  const int skh = (tid & 1) * 16;
  const ushort* ag = ctx + (size_t)(bm * 128 + srow) * Dx + skh;
  const float* bg = Wo + (size_t)(bn * 128 + srow) * Dx + skh;

  const int l15 = tid & 15, hi = (tid >> 4) & 3;
  const int w = tid >> 6;
  const int wm = (w >> 1) * 64, wn = (w & 1) * 64;

  f32x4 acc[4][4];
#pragma unroll
  for (int i = 0; i < 4; ++i)
#pragma unroll
    for (int j = 0; j < 4; ++j) acc[i][j] = {0.f, 0.f, 0.f, 0.f};

  {
    short8 a0 = *(const short8*)(ag + 0), a1 = *(const short8*)(ag + 8);
    float4 b0 = *(const float4*)(bg + 0), b1 = *(const float4*)(bg + 4);
    float4 b2 = *(const float4*)(bg + 8), b3 = *(const float4*)(bg + 12);
    *(short8*)&As[0][srow][skh] = a0;
    *(short8*)&As[0][srow][skh + 8] = a1;
    *(short8*)&Bs[0][srow][skh] = pack8(b0, b1);
    *(short8*)&Bs[0][srow][skh + 8] = pack8(b2, b3);
  }
  __syncthreads();

  int cur = 0;
  for (int kt = 0; kt < 64; ++kt) {
    short8 a0, a1;
    float4 b0, b1, b2, b3;
    if (kt < 63) {
      const ushort* ap = ag + (kt + 1) * 32;
      const float* bp = bg + (kt + 1) * 32;
      a0 = *(const short8*)(ap + 0); a1 = *(const short8*)(ap + 8);
      b0 = *(const float4*)(bp + 0); b1 = *(const float4*)(bp + 4);
      b2 = *(const float4*)(bp + 8); b3 = *(const float4*)(bp + 12);
    }
    short8 af[4], bf[4];
#pragma unroll
    for (int i = 0; i < 4; ++i)
      af[i] = *(const short8*)&As[cur][wm + i * 16 + l15][hi * 8];
#pragma unroll
    for (int j = 0; j < 4; ++j)
      bf[j] = *(const short8*)&Bs[cur][wn + j * 16 + l15][hi * 8];
#pragma unroll
    for (int i = 0; i < 4; ++i)
#pragma unroll
      for (int j = 0; j < 4; ++j) acc[i][j] = MFMA16(af[i], bf[j], acc[i][j]);
    if (kt < 63) {
      *(short8*)&As[cur ^ 1][srow][skh] = a0;
      *(short8*)&As[cur ^ 1][srow][skh + 8] = a1;
      *(short8*)&Bs[cur ^ 1][srow][skh] = pack8(b0, b1);
      *(short8*)&Bs[cur ^ 1][srow][skh + 8] = pack8(b2, b3);
    }
    __syncthreads();
    cur ^= 1;
  }

#pragma unroll
  for (int j = 0; j < 4; ++j) {
    const int n = bn * 128 + wn + j * 16 + l15;
    const float bb = bo[n];
#pragma unroll
    for (int i = 0; i < 4; ++i)
#pragma unroll
      for (int r = 0; r < 4; ++r) {
        const int m = bm * 128 + wm + i * 16 + hi * 4 + r;
        out[(size_t)m * Dx + n] = acc[i][j][r] + bb;
      }
  }
}

extern "C" void kernel_launch(void* const* d_in, const int* in_sizes, int n_in,
                              void* d_out, int out_size, void* d_ws, size_t ws_size,
                              hipStream_t stream) {
  (void)in_sizes; (void)n_in; (void)out_size; (void)ws_size;
  const float* x    = (const float*)d_in[0];
  const float* sinT = (const float*)d_in[1];
  const float* cosT = (const float*)d_in[2];
  // d_in[3] = mask (causal tril) — enforced analytically in attn_kernel
  const float* Wq = (const float*)d_in[4];
  const float* bq = (const float*)d_in[5];
  const float* Wk = (const float*)d_in[6];
  const float* bk = (const float*)d_in[7];
  const float* Wv = (const float*)d_in[8];
  const float* bv = (const float*)d_in[9];
  const float* Wo = (const float*)d_in[10];
  const float* bo = (const float*)d_in[11];
  float* out = (float*)d_out;

  const size_t NELEM = (size_t)NBx * Lx * Dx;  // 8,388,608
  ushort* qw  = (ushort*)d_ws;
  ushort* kw  = qw + NELEM;
  ushort* vw  = kw + NELEM;
  ushort* ctx = vw + NELEM;

  qkv_kernel<<<dim3(32, 16, 3), 256, 0, stream>>>(
      x, Wq, bq, Wk, bk, Wv, bv, sinT, cosT, qw, kw, vw);
  attn_kernel<<<dim3(32, 32), 256, 0, stream>>>(qw, kw, vw, ctx);
  oproj_kernel<<<dim3(32, 16), 256, 0, stream>>>(ctx, Wo, bo, out);
}

// Round 3
// 545.715 us; speedup vs baseline: 1.2311x; 1.2311x over previous
//
#include <hip/hip_runtime.h>
#include <hip/hip_bf16.h>

typedef __attribute__((ext_vector_type(8))) short short8;
typedef __attribute__((ext_vector_type(4))) ushort ushort4v;
typedef __attribute__((ext_vector_type(4))) float f32x4;

#define MFMA16(A, B, C) __builtin_amdgcn_mfma_f32_16x16x32_bf16(A, B, C, 0, 0, 0)

#define GLOAD16(gp, lp)                                        \
  __builtin_amdgcn_global_load_lds(                            \
      (__attribute__((address_space(1))) void*)(gp),           \
      (__attribute__((address_space(3))) void*)(lp), 16, 0, 0)

static constexpr int Lx = 2048, Dx = 2048, Hx = 16, HDx = 128, NBx = 2;

__device__ __forceinline__ ushort f2bu(float f) {
  __hip_bfloat16 h = __float2bfloat16(f);
  union { __hip_bfloat16 h; ushort u; } v;
  v.h = h;
  return v.u;
}

__device__ __forceinline__ short8 pack8(const float4& a, const float4& b) {
  short8 r;
  r[0] = (short)f2bu(a.x); r[1] = (short)f2bu(a.y);
  r[2] = (short)f2bu(a.z); r[3] = (short)f2bu(a.w);
  r[4] = (short)f2bu(b.x); r[5] = (short)f2bu(b.y);
  r[6] = (short)f2bu(b.z); r[7] = (short)f2bu(b.w);
  return r;
}

// ---------------------------------------------------------------------------
// One-time f32 -> bf16 conversion of x and the 4 weight matrices.
// blockIdx.y selects the tensor; grid-stride, 8 elems/thread, vectorized.
// ---------------------------------------------------------------------------
__global__ void convert_kernel(const float* __restrict__ x,
                               const float* __restrict__ Wq,
                               const float* __restrict__ Wk,
                               const float* __restrict__ Wv,
                               const float* __restrict__ Wo,
                               ushort* __restrict__ xb, ushort* __restrict__ wqb,
                               ushort* __restrict__ wkb, ushort* __restrict__ wvb,
                               ushort* __restrict__ wob) {
  const int y = blockIdx.y;
  const float* s;
  ushort* d;
  int n;
  switch (y) {
    case 0: s = x;  d = xb;  n = NBx * Lx * Dx; break;
    case 1: s = Wq; d = wqb; n = Dx * Dx; break;
    case 2: s = Wk; d = wkb; n = Dx * Dx; break;
    case 3: s = Wv; d = wvb; n = Dx * Dx; break;
    default: s = Wo; d = wob; n = Dx * Dx; break;
  }
  const int stride = gridDim.x * blockDim.x * 8;
  for (int i = (blockIdx.x * blockDim.x + threadIdx.x) * 8; i < n; i += stride) {
    float4 a = *(const float4*)(s + i);
    float4 b = *(const float4*)(s + i + 4);
    *(short8*)(d + i) = pack8(a, b);
  }
}

// ---------------------------------------------------------------------------
// QKV projection (m97 structure): bf16 in, 128x128 tile, BK=32, 4 waves,
// global_load_lds dwordx4 staging into linear LDS, double-buffered.
// Epilogue fuses bias + partial rotary + q-scale; writes bf16 [B,H,L,HD].
// ---------------------------------------------------------------------------
__global__ __launch_bounds__(256, 2) void qkv_kernel(
    const ushort* __restrict__ xb,
    const ushort* __restrict__ wqb, const float* __restrict__ bq,
    const ushort* __restrict__ wkb, const float* __restrict__ bk,
    const ushort* __restrict__ wvb, const float* __restrict__ bv,
    const float* __restrict__ sinT, const float* __restrict__ cosT,
    ushort* __restrict__ qw, ushort* __restrict__ kw, ushort* __restrict__ vw) {
  const int z = blockIdx.z;
  const ushort* W   = (z == 0) ? wqb : (z == 1) ? wkb : wvb;
  const float* bias = (z == 0) ? bq : (z == 1) ? bk : bv;
  ushort* outp      = (z == 0) ? qw : (z == 1) ? kw : vw;

  const int bm = blockIdx.x, bn = blockIdx.y;
  const int tid = threadIdx.x;
  const int lane = tid & 63;
  const int w = tid >> 6;
  const int l15 = tid & 15, hi = (tid >> 4) & 3;
  const int wm = (w >> 1) * 64, wn = (w & 1) * 64;

  __shared__ ushort As[2][128 * 32];
  __shared__ ushort Bs[2][128 * 32];

  // staging geometry: wave w stages chunks {2w, 2w+1}; chunk c = rows
  // [16c,16c+16), 1 KiB, lane l -> row c*16+(l>>2), col (l&3)*8.
  const int cA = w * 2;
  const int srow = cA * 16 + (lane >> 2);
  const int scol = (lane & 3) * 8;
  const ushort* aSrc = xb + (size_t)(bm * 128 + srow) * Dx + scol;
  const ushort* bSrc = W + (size_t)(bn * 128 + srow) * Dx + scol;
  const int ldsOff = cA * 512;  // elems

#define STAGE_QKV(buf, kt)                                           \
  do {                                                               \
    const ushort* ap = aSrc + (kt) * 32;                             \
    const ushort* bp = bSrc + (kt) * 32;                             \
    GLOAD16(ap, &As[buf][ldsOff]);                                   \
    GLOAD16(ap + 16 * Dx, &As[buf][ldsOff + 512]);                   \
    GLOAD16(bp, &Bs[buf][ldsOff]);                                   \
    GLOAD16(bp + 16 * Dx, &Bs[buf][ldsOff + 512]);                   \
  } while (0)

  f32x4 acc[4][4];
#pragma unroll
  for (int i = 0; i < 4; ++i)
#pragma unroll
    for (int j = 0; j < 4; ++j) acc[i][j] = {0.f, 0.f, 0.f, 0.f};

  STAGE_QKV(0, 0);
  __syncthreads();  // drains vmcnt before first frag reads

  int cur = 0;
  for (int kt = 0; kt < 64; ++kt) {
    if (kt < 63) STAGE_QKV(cur ^ 1, kt + 1);
    short8 af[4], bf[4];
#pragma unroll
    for (int i = 0; i < 4; ++i)
      af[i] = *(const short8*)&As[cur][(wm + i * 16 + l15) * 32 + hi * 8];
#pragma unroll
    for (int j = 0; j < 4; ++j)
      bf[j] = *(const short8*)&Bs[cur][(wn + j * 16 + l15) * 32 + hi * 8];
#pragma unroll
    for (int i = 0; i < 4; ++i)
#pragma unroll
      for (int j = 0; j < 4; ++j) acc[i][j] = MFMA16(af[i], bf[j], acc[i][j]);
    __syncthreads();
    cur ^= 1;
  }
#undef STAGE_QKV

  // epilogue: bias + rotary(first half of each head, q&k) + q scale
  const float rsHD = 0.08838834764831845f;  // 1/sqrt(128)
#pragma unroll
  for (int j = 0; j < 4; ++j) {
    const int n = bn * 128 + wn + j * 16 + l15;
    const int h = n >> 7, d = n & 127;
    const float bb = bias[n];
#pragma unroll
    for (int i = 0; i < 4; ++i) {
#pragma unroll
      for (int r = 0; r < 4; ++r) {
        const int m = bm * 128 + wm + i * 16 + hi * 4 + r;
        const int b = m >> 11, l = m & (Lx - 1);
        float v = acc[i][j][r] + bb;
        if (z < 2 && d < 64) v *= (cosT[l * 64 + d] - sinT[l * 64 + d]);
        if (z == 0) v *= rsHD;
        outp[(size_t)((b * Hx + h) * Lx + l) * HDx + d] = f2bu(v);
      }
    }
  }
}

// ---------------------------------------------------------------------------
// Causal flash attention (unchanged this round). 4 waves x 16 q-rows,
// KVBLK=64, bf16 MFMA, wave-parallel online softmax.
// ---------------------------------------------------------------------------
__global__ __launch_bounds__(256, 2) void attn_kernel(
    const ushort* __restrict__ qw, const ushort* __restrict__ kw,
    const ushort* __restrict__ vw, ushort* __restrict__ ctx) {
  const int qt = (int)(gridDim.x - 1) - (int)blockIdx.x;  // heavy tiles first
  const int bh = blockIdx.y;
  const int b = bh >> 4, h = bh & 15;
  const int tid = threadIdx.x;
  const int w = tid >> 6, l15 = tid & 15, hi = (tid >> 4) & 3;

  const ushort* Q = qw + (size_t)bh * Lx * HDx;
  const ushort* K = kw + (size_t)bh * Lx * HDx;
  const ushort* V = vw + (size_t)bh * Lx * HDx;

  __shared__ ushort Ks[64][136];
  __shared__ ushort Vt[128][72];
  __shared__ ushort Ps[4][16][72];

  short8 qf[4];
  {
    const ushort* qr = Q + (size_t)(qt * 64 + w * 16 + l15) * HDx + hi * 8;
#pragma unroll
    for (int ds = 0; ds < 4; ++ds) qf[ds] = *(const short8*)(qr + ds * 32);
  }

  f32x4 o[8];
#pragma unroll
  for (int df = 0; df < 8; ++df) o[df] = {0.f, 0.f, 0.f, 0.f};
  float mr[4], lr[4];
#pragma unroll
  for (int r = 0; r < 4; ++r) { mr[r] = -1e30f; lr[r] = 0.f; }

  const int skrow = tid >> 2, skd = (tid & 3) * 32;
  const int svk = (tid & 15) * 4, svd = (tid >> 4) * 8;

  for (int kv = 0; kv <= qt; ++kv) {
    __syncthreads();
    {
      const ushort* kp = K + (size_t)(kv * 64 + skrow) * HDx + skd;
      short8 k0 = *(const short8*)(kp + 0), k1 = *(const short8*)(kp + 8);
      short8 k2 = *(const short8*)(kp + 16), k3 = *(const short8*)(kp + 24);
      *(short8*)&Ks[skrow][skd + 0] = k0;
      *(short8*)&Ks[skrow][skd + 8] = k1;
      *(short8*)&Ks[skrow][skd + 16] = k2;
      *(short8*)&Ks[skrow][skd + 24] = k3;
    }
    {
      const ushort* vp = V + (size_t)(kv * 64 + svk) * HDx + svd;
      short8 r0 = *(const short8*)(vp);
      short8 r1 = *(const short8*)(vp + HDx);
      short8 r2 = *(const short8*)(vp + 2 * HDx);
      short8 r3 = *(const short8*)(vp + 3 * HDx);
#pragma unroll
      for (int j = 0; j < 8; ++j) {
        ushort4v pk;
        pk[0] = (ushort)r0[j]; pk[1] = (ushort)r1[j];
        pk[2] = (ushort)r2[j]; pk[3] = (ushort)r3[j];
        *(ushort4v*)&Vt[svd + j][svk] = pk;
      }
    }
    __syncthreads();

    f32x4 s[4];
#pragma unroll
    for (int kf = 0; kf < 4; ++kf) s[kf] = {0.f, 0.f, 0.f, 0.f};
#pragma unroll
    for (int kf = 0; kf < 4; ++kf)
#pragma unroll
      for (int ds = 0; ds < 4; ++ds) {
        short8 kb = *(const short8*)&Ks[kf * 16 + l15][ds * 32 + hi * 8];
        s[kf] = MFMA16(qf[ds], kb, s[kf]);
      }

    if (kv == qt) {
#pragma unroll
      for (int kf = 0; kf < 4; ++kf)
#pragma unroll
        for (int r = 0; r < 4; ++r)
          if (kf * 16 + l15 > w * 16 + hi * 4 + r) s[kf][r] = -1e30f;
    }

    float ml[4];
#pragma unroll
    for (int r = 0; r < 4; ++r)
      ml[r] = fmaxf(fmaxf(s[0][r], s[1][r]), fmaxf(s[2][r], s[3][r]));
#pragma unroll
    for (int off = 1; off <= 8; off <<= 1)
#pragma unroll
      for (int r = 0; r < 4; ++r) ml[r] = fmaxf(ml[r], __shfl_xor(ml[r], off));
    float scl[4];
#pragma unroll
    for (int r = 0; r < 4; ++r) {
      float mn = fmaxf(mr[r], ml[r]);
      scl[r] = __expf(mr[r] - mn);
      mr[r] = mn;
    }
    float ll[4] = {0.f, 0.f, 0.f, 0.f};
#pragma unroll
    for (int kf = 0; kf < 4; ++kf)
#pragma unroll
      for (int r = 0; r < 4; ++r) {
        float p = __expf(s[kf][r] - mr[r]);
        s[kf][r] = p;
        ll[r] += p;
      }
#pragma unroll
    for (int off = 1; off <= 8; off <<= 1)
#pragma unroll
      for (int r = 0; r < 4; ++r) ll[r] += __shfl_xor(ll[r], off);
#pragma unroll
    for (int r = 0; r < 4; ++r) lr[r] = lr[r] * scl[r] + ll[r];
#pragma unroll
    for (int df = 0; df < 8; ++df)
#pragma unroll
      for (int r = 0; r < 4; ++r) o[df][r] *= scl[r];

#pragma unroll
    for (int kf = 0; kf < 4; ++kf)
#pragma unroll
      for (int r = 0; r < 4; ++r)
        Ps[w][hi * 4 + r][kf * 16 + l15] = f2bu(s[kf][r]);

    short8 pa0 = *(const short8*)&Ps[w][l15][hi * 8];
    short8 pa1 = *(const short8*)&Ps[w][l15][32 + hi * 8];
#pragma unroll
    for (int df = 0; df < 8; ++df) {
      short8 v0 = *(const short8*)&Vt[df * 16 + l15][hi * 8];
      short8 v1 = *(const short8*)&Vt[df * 16 + l15][32 + hi * 8];
      o[df] = MFMA16(pa0, v0, o[df]);
      o[df] = MFMA16(pa1, v1, o[df]);
    }
  }

  float inv[4];
#pragma unroll
  for (int r = 0; r < 4; ++r) inv[r] = 1.0f / lr[r];
  ushort* cp = ctx + (size_t)(b * Lx + qt * 64 + w * 16) * Dx + h * HDx;
#pragma unroll
  for (int df = 0; df < 8; ++df)
#pragma unroll
    for (int r = 0; r < 4; ++r)
      cp[(size_t)(hi * 4 + r) * Dx + df * 16 + l15] = f2bu(o[df][r] * inv[r]);
}

// ---------------------------------------------------------------------------
// Output projection (m97 structure): out = ctx @ Wo.T + bo, f32 out + bias.
// ---------------------------------------------------------------------------
__global__ __launch_bounds__(256, 2) void oproj_kernel(
    const ushort* __restrict__ ctx, const ushort* __restrict__ wob,
    const float* __restrict__ bo, float* __restrict__ out) {
  const int bm = blockIdx.x, bn = blockIdx.y;
  const int tid = threadIdx.x;
  const int lane = tid & 63;
  const int w = tid >> 6;
  const int l15 = tid & 15, hi = (tid >> 4) & 3;
  const int wm = (w >> 1) * 64, wn = (w & 1) * 64;

  __shared__ ushort As[2][128 * 32];
  __shared__ ushort Bs[2][128 * 32];

  const int cA = w * 2;
  const int srow = cA * 16 + (lane >> 2);
  const int scol = (lane & 3) * 8;
  const ushort* aSrc = ctx + (size_t)(bm * 128 + srow) * Dx + scol;
  const ushort* bSrc = wob + (size_t)(bn * 128 + srow) * Dx + scol;
  const int ldsOff = cA * 512;

#define STAGE_O(buf, kt)                                             \
  do {                                                               \
    const ushort* ap = aSrc + (kt) * 32;                             \
    const ushort* bp = bSrc + (kt) * 32;                             \
    GLOAD16(ap, &As[buf][ldsOff]);                                   \
    GLOAD16(ap + 16 * Dx, &As[buf][ldsOff + 512]);                   \
    GLOAD16(bp, &Bs[buf][ldsOff]);                                   \
    GLOAD16(bp + 16 * Dx, &Bs[buf][ldsOff + 512]);                   \
  } while (0)

  f32x4 acc[4][4];
#pragma unroll
  for (int i = 0; i < 4; ++i)
#pragma unroll
    for (int j = 0; j < 4; ++j) acc[i][j] = {0.f, 0.f, 0.f, 0.f};

  STAGE_O(0, 0);
  __syncthreads();

  int cur = 0;
  for (int kt = 0; kt < 64; ++kt) {
    if (kt < 63) STAGE_O(cur ^ 1, kt + 1);
    short8 af[4], bf[4];
#pragma unroll
    for (int i = 0; i < 4; ++i)
      af[i] = *(const short8*)&As[cur][(wm + i * 16 + l15) * 32 + hi * 8];
#pragma unroll
    for (int j = 0; j < 4; ++j)
      bf[j] = *(const short8*)&Bs[cur][(wn + j * 16 + l15) * 32 + hi * 8];
#pragma unroll
    for (int i = 0; i < 4; ++i)
#pragma unroll
      for (int j = 0; j < 4; ++j) acc[i][j] = MFMA16(af[i], bf[j], acc[i][j]);
    __syncthreads();
    cur ^= 1;
  }
#undef STAGE_O

#pragma unroll
  for (int j = 0; j < 4; ++j) {
    const int n = bn * 128 + wn + j * 16 + l15;
    const float bb = bo[n];
#pragma unroll
    for (int i = 0; i < 4; ++i)
#pragma unroll
      for (int r = 0; r < 4; ++r) {
        const int m = bm * 128 + wm + i * 16 + hi * 4 + r;
        out[(size_t)m * Dx + n] = acc[i][j][r] + bb;
      }
  }
}

extern "C" void kernel_launch(void* const* d_in, const int* in_sizes, int n_in,
                              void* d_out, int out_size, void* d_ws, size_t ws_size,
                              hipStream_t stream) {
  (void)in_sizes; (void)n_in; (void)out_size; (void)ws_size;
  const float* x    = (const float*)d_in[0];
  const float* sinT = (const float*)d_in[1];
  const float* cosT = (const float*)d_in[2];
  // d_in[3] = mask (causal tril) — enforced analytically in attn_kernel
  const float* Wq = (const float*)d_in[4];
  const float* bq = (const float*)d_in[5];
  const float* Wk = (const float*)d_in[6];
  const float* bk = (const float*)d_in[7];
  const float* Wv = (const float*)d_in[8];
  const float* bv = (const float*)d_in[9];
  const float* Wo = (const float*)d_in[10];
  const float* bo = (const float*)d_in[11];
  float* out = (float*)d_out;

  const size_t N = (size_t)NBx * Lx * Dx;  // 8,388,608
  const size_t M = (size_t)Dx * Dx;        // 4,194,304
  ushort* qw  = (ushort*)d_ws;
  ushort* kw  = qw + N;
  ushort* vw  = kw + N;
  ushort* ctx = vw + N;
  ushort* xb  = ctx;  // alias: xb consumed by qkv before attn writes ctx
  ushort* wqb = ctx + N;
  ushort* wkb = wqb + M;
  ushort* wvb = wkb + M;
  ushort* wob = wvb + M;

  convert_kernel<<<dim3(1024, 5), 256, 0, stream>>>(
      x, Wq, Wk, Wv, Wo, xb, wqb, wkb, wvb, wob);
  qkv_kernel<<<dim3(32, 16, 3), 256, 0, stream>>>(
      xb, wqb, bq, wkb, bk, wvb, bv, sinT, cosT, qw, kw, vw);
  attn_kernel<<<dim3(32, 32), 256, 0, stream>>>(qw, kw, vw, ctx);
  oproj_kernel<<<dim3(32, 16), 256, 0, stream>>>(ctx, wob, bo, out);
}

// Round 5
// 456.144 us; speedup vs baseline: 1.4729x; 1.1964x over previous
//
#include <hip/hip_runtime.h>
#include <hip/hip_bf16.h>

typedef __attribute__((ext_vector_type(8))) short short8;
typedef __attribute__((ext_vector_type(4))) ushort ushort4v;
typedef __attribute__((ext_vector_type(4))) float f32x4;

#define MFMA16(A, B, C) __builtin_amdgcn_mfma_f32_16x16x32_bf16(A, B, C, 0, 0, 0)

#define GLOAD16(gp, lp)                                        \
  __builtin_amdgcn_global_load_lds(                            \
      (__attribute__((address_space(1))) void*)(gp),           \
      (__attribute__((address_space(3))) void*)(lp), 16, 0, 0)

static constexpr int Lx = 2048, Dx = 2048, Hx = 16, HDx = 128, NBx = 2;

__device__ __forceinline__ ushort f2bu(float f) {
  __hip_bfloat16 h = __float2bfloat16(f);
  union { __hip_bfloat16 h; ushort u; } v;
  v.h = h;
  return v.u;
}

__device__ __forceinline__ short8 pack8(const float4& a, const float4& b) {
  short8 r;
  r[0] = (short)f2bu(a.x); r[1] = (short)f2bu(a.y);
  r[2] = (short)f2bu(a.z); r[3] = (short)f2bu(a.w);
  r[4] = (short)f2bu(b.x); r[5] = (short)f2bu(b.y);
  r[6] = (short)f2bu(b.z); r[7] = (short)f2bu(b.w);
  return r;
}

// ---------------------------------------------------------------------------
// One-time f32 -> bf16 conversion of x and the 4 weight matrices.
// ---------------------------------------------------------------------------
__global__ void convert_kernel(const float* __restrict__ x,
                               const float* __restrict__ Wq,
                               const float* __restrict__ Wk,
                               const float* __restrict__ Wv,
                               const float* __restrict__ Wo,
                               ushort* __restrict__ xb, ushort* __restrict__ wqb,
                               ushort* __restrict__ wkb, ushort* __restrict__ wvb,
                               ushort* __restrict__ wob) {
  const int y = blockIdx.y;
  const float* s;
  ushort* d;
  int n;
  switch (y) {
    case 0: s = x;  d = xb;  n = NBx * Lx * Dx; break;
    case 1: s = Wq; d = wqb; n = Dx * Dx; break;
    case 2: s = Wk; d = wkb; n = Dx * Dx; break;
    case 3: s = Wv; d = wvb; n = Dx * Dx; break;
    default: s = Wo; d = wob; n = Dx * Dx; break;
  }
  const int stride = gridDim.x * blockDim.x * 8;
  for (int i = (blockIdx.x * blockDim.x + threadIdx.x) * 8; i < n; i += stride) {
    float4 a = *(const float4*)(s + i);
    float4 b = *(const float4*)(s + i + 4);
    *(short8*)(d + i) = pack8(a, b);
  }
}

// ---------------------------------------------------------------------------
// QKV projection (m97 structure) — unchanged from R3.
// ---------------------------------------------------------------------------
__global__ __launch_bounds__(256, 2) void qkv_kernel(
    const ushort* __restrict__ xb,
    const ushort* __restrict__ wqb, const float* __restrict__ bq,
    const ushort* __restrict__ wkb, const float* __restrict__ bk,
    const ushort* __restrict__ wvb, const float* __restrict__ bv,
    const float* __restrict__ sinT, const float* __restrict__ cosT,
    ushort* __restrict__ qw, ushort* __restrict__ kw, ushort* __restrict__ vw) {
  const int z = blockIdx.z;
  const ushort* W   = (z == 0) ? wqb : (z == 1) ? wkb : wvb;
  const float* bias = (z == 0) ? bq : (z == 1) ? bk : bv;
  ushort* outp      = (z == 0) ? qw : (z == 1) ? kw : vw;

  const int bm = blockIdx.x, bn = blockIdx.y;
  const int tid = threadIdx.x;
  const int lane = tid & 63;
  const int w = tid >> 6;
  const int l15 = tid & 15, hi = (tid >> 4) & 3;
  const int wm = (w >> 1) * 64, wn = (w & 1) * 64;

  __shared__ ushort As[2][128 * 32];
  __shared__ ushort Bs[2][128 * 32];

  const int cA = w * 2;
  const int srow = cA * 16 + (lane >> 2);
  const int scol = (lane & 3) * 8;
  const ushort* aSrc = xb + (size_t)(bm * 128 + srow) * Dx + scol;
  const ushort* bSrc = W + (size_t)(bn * 128 + srow) * Dx + scol;
  const int ldsOff = cA * 512;

#define STAGE_QKV(buf, kt)                                           \
  do {                                                               \
    const ushort* ap = aSrc + (kt) * 32;                             \
    const ushort* bp = bSrc + (kt) * 32;                             \
    GLOAD16(ap, &As[buf][ldsOff]);                                   \
    GLOAD16(ap + 16 * Dx, &As[buf][ldsOff + 512]);                   \
    GLOAD16(bp, &Bs[buf][ldsOff]);                                   \
    GLOAD16(bp + 16 * Dx, &Bs[buf][ldsOff + 512]);                   \
  } while (0)

  f32x4 acc[4][4];
#pragma unroll
  for (int i = 0; i < 4; ++i)
#pragma unroll
    for (int j = 0; j < 4; ++j) acc[i][j] = {0.f, 0.f, 0.f, 0.f};

  STAGE_QKV(0, 0);
  __syncthreads();

  int cur = 0;
  for (int kt = 0; kt < 64; ++kt) {
    if (kt < 63) STAGE_QKV(cur ^ 1, kt + 1);
    short8 af[4], bf[4];
#pragma unroll
    for (int i = 0; i < 4; ++i)
      af[i] = *(const short8*)&As[cur][(wm + i * 16 + l15) * 32 + hi * 8];
#pragma unroll
    for (int j = 0; j < 4; ++j)
      bf[j] = *(const short8*)&Bs[cur][(wn + j * 16 + l15) * 32 + hi * 8];
#pragma unroll
    for (int i = 0; i < 4; ++i)
#pragma unroll
      for (int j = 0; j < 4; ++j) acc[i][j] = MFMA16(af[i], bf[j], acc[i][j]);
    __syncthreads();
    cur ^= 1;
  }
#undef STAGE_QKV

  const float rsHD = 0.08838834764831845f;  // 1/sqrt(128)
#pragma unroll
  for (int j = 0; j < 4; ++j) {
    const int n = bn * 128 + wn + j * 16 + l15;
    const int h = n >> 7, d = n & 127;
    const float bb = bias[n];
#pragma unroll
    for (int i = 0; i < 4; ++i) {
#pragma unroll
      for (int r = 0; r < 4; ++r) {
        const int m = bm * 128 + wm + i * 16 + hi * 4 + r;
        const int b = m >> 11, l = m & (Lx - 1);
        float v = acc[i][j][r] + bb;
        if (z < 2 && d < 64) v *= (cosT[l * 64 + d] - sinT[l * 64 + d]);
        if (z == 0) v *= rsHD;
        outp[(size_t)((b * Hx + h) * Lx + l) * HDx + d] = f2bu(v);
      }
    }
  }
}

// ---------------------------------------------------------------------------
// Causal flash attention v2.
//  - Pair-balanced grid: block x = pair index i, processes qt=i then qt=31-i
//    (every block: exactly 33 kv-tile iterations -> no tail imbalance).
//  - T14 async-STAGE: next tile's global loads issued before current tile's
//    compute; single LDS buffer, ds_writes at loop top after barrier.
//  - Ps/Vt padded to 76 (stride 152B -> 2-way max on writes, clean reads).
//  - T5 setprio around MFMA clusters.
// ---------------------------------------------------------------------------
__global__ __launch_bounds__(256, 2) void attn_kernel(
    const ushort* __restrict__ qw, const ushort* __restrict__ kw,
    const ushort* __restrict__ vw, ushort* __restrict__ ctx) {
  const int pair = blockIdx.x;  // 0..15
  const int bh = blockIdx.y;
  const int b = bh >> 4, h = bh & 15;
  const int tid = threadIdx.x;
  const int w = tid >> 6, l15 = tid & 15, hi = (tid >> 4) & 3;

  const ushort* Q = qw + (size_t)bh * Lx * HDx;
  const ushort* K = kw + (size_t)bh * Lx * HDx;
  const ushort* V = vw + (size_t)bh * Lx * HDx;

  __shared__ ushort Ks[64][136];
  __shared__ ushort Vt[128][76];
  __shared__ ushort Ps[4][16][76];

  const int skrow = tid >> 2, skd = (tid & 3) * 32;     // K staging geometry
  const int svk = (tid & 15) * 4, svd = (tid >> 4) * 8; // V staging geometry

  for (int seg = 0; seg < 2; ++seg) {
    const int qt = seg ? (31 - pair) : pair;

    short8 qf[4];
    {
      const ushort* qr = Q + (size_t)(qt * 64 + w * 16 + l15) * HDx + hi * 8;
#pragma unroll
      for (int ds = 0; ds < 4; ++ds) qf[ds] = *(const short8*)(qr + ds * 32);
    }

    f32x4 o[8];
#pragma unroll
    for (int df = 0; df < 8; ++df) o[df] = {0.f, 0.f, 0.f, 0.f};
    float mr[4], lr[4];
#pragma unroll
    for (int r = 0; r < 4; ++r) { mr[r] = -1e30f; lr[r] = 0.f; }

    // prologue: prefetch kv=0 into regs
    short8 kreg[4], vreg[4];
    {
      const ushort* kp = K + (size_t)skrow * HDx + skd;
      kreg[0] = *(const short8*)(kp + 0);  kreg[1] = *(const short8*)(kp + 8);
      kreg[2] = *(const short8*)(kp + 16); kreg[3] = *(const short8*)(kp + 24);
      const ushort* vp = V + (size_t)svk * HDx + svd;
      vreg[0] = *(const short8*)(vp);
      vreg[1] = *(const short8*)(vp + HDx);
      vreg[2] = *(const short8*)(vp + 2 * HDx);
      vreg[3] = *(const short8*)(vp + 3 * HDx);
    }

    for (int kv = 0; kv <= qt; ++kv) {
      __syncthreads();  // LDS free (prev tile's reads / prev segment done)
      // regs -> LDS
      *(short8*)&Ks[skrow][skd + 0] = kreg[0];
      *(short8*)&Ks[skrow][skd + 8] = kreg[1];
      *(short8*)&Ks[skrow][skd + 16] = kreg[2];
      *(short8*)&Ks[skrow][skd + 24] = kreg[3];
#pragma unroll
      for (int j = 0; j < 8; ++j) {
        ushort4v pk;
        pk[0] = (ushort)vreg[0][j]; pk[1] = (ushort)vreg[1][j];
        pk[2] = (ushort)vreg[2][j]; pk[3] = (ushort)vreg[3][j];
        *(ushort4v*)&Vt[svd + j][svk] = pk;
      }
      __syncthreads();

      if (kv < qt) {  // issue next tile's loads early; latency hides under compute
        const ushort* kp = K + (size_t)((kv + 1) * 64 + skrow) * HDx + skd;
        kreg[0] = *(const short8*)(kp + 0);  kreg[1] = *(const short8*)(kp + 8);
        kreg[2] = *(const short8*)(kp + 16); kreg[3] = *(const short8*)(kp + 24);
        const ushort* vp = V + (size_t)((kv + 1) * 64 + svk) * HDx + svd;
        vreg[0] = *(const short8*)(vp);
        vreg[1] = *(const short8*)(vp + HDx);
        vreg[2] = *(const short8*)(vp + 2 * HDx);
        vreg[3] = *(const short8*)(vp + 3 * HDx);
      }

      // S = Q K^T
      f32x4 s[4];
#pragma unroll
      for (int kf = 0; kf < 4; ++kf) s[kf] = {0.f, 0.f, 0.f, 0.f};
      __builtin_amdgcn_s_setprio(1);
#pragma unroll
      for (int kf = 0; kf < 4; ++kf)
#pragma unroll
        for (int ds = 0; ds < 4; ++ds) {
          short8 kb = *(const short8*)&Ks[kf * 16 + l15][ds * 32 + hi * 8];
          s[kf] = MFMA16(qf[ds], kb, s[kf]);
        }
      __builtin_amdgcn_s_setprio(0);

      if (kv == qt) {  // diagonal: causal mask
#pragma unroll
        for (int kf = 0; kf < 4; ++kf)
#pragma unroll
          for (int r = 0; r < 4; ++r)
            if (kf * 16 + l15 > w * 16 + hi * 4 + r) s[kf][r] = -1e30f;
      }

      // online softmax
      float ml[4];
#pragma unroll
      for (int r = 0; r < 4; ++r)
        ml[r] = fmaxf(fmaxf(s[0][r], s[1][r]), fmaxf(s[2][r], s[3][r]));
#pragma unroll
      for (int off = 1; off <= 8; off <<= 1)
#pragma unroll
        for (int r = 0; r < 4; ++r) ml[r] = fmaxf(ml[r], __shfl_xor(ml[r], off));
      float scl[4];
#pragma unroll
      for (int r = 0; r < 4; ++r) {
        float mn = fmaxf(mr[r], ml[r]);
        scl[r] = __expf(mr[r] - mn);
        mr[r] = mn;
      }
      float ll[4] = {0.f, 0.f, 0.f, 0.f};
#pragma unroll
      for (int kf = 0; kf < 4; ++kf)
#pragma unroll
        for (int r = 0; r < 4; ++r) {
          float p = __expf(s[kf][r] - mr[r]);
          s[kf][r] = p;
          ll[r] += p;
        }
#pragma unroll
      for (int off = 1; off <= 8; off <<= 1)
#pragma unroll
        for (int r = 0; r < 4; ++r) ll[r] += __shfl_xor(ll[r], off);
#pragma unroll
      for (int r = 0; r < 4; ++r) lr[r] = lr[r] * scl[r] + ll[r];
#pragma unroll
      for (int df = 0; df < 8; ++df)
#pragma unroll
        for (int r = 0; r < 4; ++r) o[df][r] *= scl[r];

      // P -> per-wave LDS (C-layout -> A-layout)
#pragma unroll
      for (int kf = 0; kf < 4; ++kf)
#pragma unroll
        for (int r = 0; r < 4; ++r)
          Ps[w][hi * 4 + r][kf * 16 + l15] = f2bu(s[kf][r]);

      short8 pa0 = *(const short8*)&Ps[w][l15][hi * 8];
      short8 pa1 = *(const short8*)&Ps[w][l15][32 + hi * 8];
      __builtin_amdgcn_s_setprio(1);
#pragma unroll
      for (int df = 0; df < 8; ++df) {
        short8 v0 = *(const short8*)&Vt[df * 16 + l15][hi * 8];
        short8 v1 = *(const short8*)&Vt[df * 16 + l15][32 + hi * 8];
        o[df] = MFMA16(pa0, v0, o[df]);
        o[df] = MFMA16(pa1, v1, o[df]);
      }
      __builtin_amdgcn_s_setprio(0);
    }

    // epilogue for this segment
    float inv[4];
#pragma unroll
    for (int r = 0; r < 4; ++r) inv[r] = 1.0f / lr[r];
    ushort* cp = ctx + (size_t)(b * Lx + qt * 64 + w * 16) * Dx + h * HDx;
#pragma unroll
    for (int df = 0; df < 8; ++df)
#pragma unroll
      for (int r = 0; r < 4; ++r)
        cp[(size_t)(hi * 4 + r) * Dx + df * 16 + l15] = f2bu(o[df][r] * inv[r]);
  }
}

// ---------------------------------------------------------------------------
// Output projection (m97 structure) — unchanged from R3.
// ---------------------------------------------------------------------------
__global__ __launch_bounds__(256, 2) void oproj_kernel(
    const ushort* __restrict__ ctx, const ushort* __restrict__ wob,
    const float* __restrict__ bo, float* __restrict__ out) {
  const int bm = blockIdx.x, bn = blockIdx.y;
  const int tid = threadIdx.x;
  const int lane = tid & 63;
  const int w = tid >> 6;
  const int l15 = tid & 15, hi = (tid >> 4) & 3;
  const int wm = (w >> 1) * 64, wn = (w & 1) * 64;

  __shared__ ushort As[2][128 * 32];
  __shared__ ushort Bs[2][128 * 32];

  const int cA = w * 2;
  const int srow = cA * 16 + (lane >> 2);
  const int scol = (lane & 3) * 8;
  const ushort* aSrc = ctx + (size_t)(bm * 128 + srow) * Dx + scol;
  const ushort* bSrc = wob + (size_t)(bn * 128 + srow) * Dx + scol;
  const int ldsOff = cA * 512;

#define STAGE_O(buf, kt)                                             \
  do {                                                               \
    const ushort* ap = aSrc + (kt) * 32;                             \
    const ushort* bp = bSrc + (kt) * 32;                             \
    GLOAD16(ap, &As[buf][ldsOff]);                                   \
    GLOAD16(ap + 16 * Dx, &As[buf][ldsOff + 512]);                   \
    GLOAD16(bp, &Bs[buf][ldsOff]);                                   \
    GLOAD16(bp + 16 * Dx, &Bs[buf][ldsOff + 512]);                   \
  } while (0)

  f32x4 acc[4][4];
#pragma unroll
  for (int i = 0; i < 4; ++i)
#pragma unroll
    for (int j = 0; j < 4; ++j) acc[i][j] = {0.f, 0.f, 0.f, 0.f};

  STAGE_O(0, 0);
  __syncthreads();

  int cur = 0;
  for (int kt = 0; kt < 64; ++kt) {
    if (kt < 63) STAGE_O(cur ^ 1, kt + 1);
    short8 af[4], bf[4];
#pragma unroll
    for (int i = 0; i < 4; ++i)
      af[i] = *(const short8*)&As[cur][(wm + i * 16 + l15) * 32 + hi * 8];
#pragma unroll
    for (int j = 0; j < 4; ++j)
      bf[j] = *(const short8*)&Bs[cur][(wn + j * 16 + l15) * 32 + hi * 8];
#pragma unroll
    for (int i = 0; i < 4; ++i)
#pragma unroll
      for (int j = 0; j < 4; ++j) acc[i][j] = MFMA16(af[i], bf[j], acc[i][j]);
    __syncthreads();
    cur ^= 1;
  }
#undef STAGE_O

#pragma unroll
  for (int j = 0; j < 4; ++j) {
    const int n = bn * 128 + wn + j * 16 + l15;
    const float bb = bo[n];
#pragma unroll
    for (int i = 0; i < 4; ++i)
#pragma unroll
      for (int r = 0; r < 4; ++r) {
        const int m = bm * 128 + wm + i * 16 + hi * 4 + r;
        out[(size_t)m * Dx + n] = acc[i][j][r] + bb;
      }
  }
}

extern "C" void kernel_launch(void* const* d_in, const int* in_sizes, int n_in,
                              void* d_out, int out_size, void* d_ws, size_t ws_size,
                              hipStream_t stream) {
  (void)in_sizes; (void)n_in; (void)out_size; (void)ws_size;
  const float* x    = (const float*)d_in[0];
  const float* sinT = (const float*)d_in[1];
  const float* cosT = (const float*)d_in[2];
  // d_in[3] = mask (causal tril) — enforced analytically in attn_kernel
  const float* Wq = (const float*)d_in[4];
  const float* bq = (const float*)d_in[5];
  const float* Wk = (const float*)d_in[6];
  const float* bk = (const float*)d_in[7];
  const float* Wv = (const float*)d_in[8];
  const float* bv = (const float*)d_in[9];
  const float* Wo = (const float*)d_in[10];
  const float* bo = (const float*)d_in[11];
  float* out = (float*)d_out;

  const size_t N = (size_t)NBx * Lx * Dx;  // 8,388,608
  const size_t M = (size_t)Dx * Dx;        // 4,194,304
  ushort* qw  = (ushort*)d_ws;
  ushort* kw  = qw + N;
  ushort* vw  = kw + N;
  ushort* ctx = vw + N;
  ushort* xb  = ctx;  // alias: xb consumed by qkv before attn writes ctx
  ushort* wqb = ctx + N;
  ushort* wkb = wqb + M;
  ushort* wvb = wkb + M;
  ushort* wob = wvb + M;

  convert_kernel<<<dim3(1024, 5), 256, 0, stream>>>(
      x, Wq, Wk, Wv, Wo, xb, wqb, wkb, wvb, wob);
  qkv_kernel<<<dim3(32, 16, 3), 256, 0, stream>>>(
      xb, wqb, bq, wkb, bk, wvb, bv, sinT, cosT, qw, kw, vw);
  attn_kernel<<<dim3(16, 32), 256, 0, stream>>>(qw, kw, vw, ctx);
  oproj_kernel<<<dim3(32, 16), 256, 0, stream>>>(ctx, wob, bo, out);
}